// Round 8
// baseline (1903.637 us; speedup 1.0000x reference)
//
#include <hip/hip_runtime.h>

typedef unsigned int uint;
typedef unsigned short ushort;

typedef __attribute__((ext_vector_type(8))) __bf16 bf16x8;
typedef __attribute__((ext_vector_type(4))) float f32x4;

#define B_ 64
#define S_ 256
#define D_ 512
#define H_ 8
#define DFF_ 2048
#define V_ 128
#define L_ 6
#define BS_ (B_ * S_)

__device__ __forceinline__ float blo(uint u) { return __uint_as_float(u << 16); }
__device__ __forceinline__ float bhi(uint u) { return __uint_as_float(u & 0xffff0000u); }
__device__ __forceinline__ float b2f(ushort u) { return __uint_as_float(((uint)u) << 16); }
__device__ __forceinline__ ushort f2b(float f) {
  uint u = __float_as_uint(f);
  return (ushort)((u + 0x7fffu + ((u >> 16) & 1u)) >> 16);  // RTNE
}
__device__ __forceinline__ uint pack2(float a, float b) {
  return (uint)f2b(a) | ((uint)f2b(b) << 16);
}

#define GLOAD16(gp, lp)                                                        \
  __builtin_amdgcn_global_load_lds(                                            \
      (const __attribute__((address_space(1))) void*)(gp),                     \
      (__attribute__((address_space(3))) void*)(lp), 16, 0, 0)

// -------- fp32 -> bf16 bulk conversion (one-time per launch) ---------------
__global__ __launch_bounds__(256) void conv_kernel(const float* __restrict__ src,
                                                   ushort* __restrict__ dst) {
  size_t p = (size_t)blockIdx.x * 256 + threadIdx.x;
  float2 v = ((const float2*)src)[p];
  ((uint*)dst)[p] = pack2(v.x, v.y);
}

// -------- embedding: x16 = bf16(emb[tgt] + pos); emb/pos fp32 ---------------
__global__ __launch_bounds__(256) void embed_kernel(
    const int* __restrict__ tgt, const float* __restrict__ emb,
    const float* __restrict__ pos, ushort* __restrict__ x16) {
  int p = blockIdx.x * 256 + threadIdx.x;
  int row = p >> 8;
  int d2 = p & 255;
  int s = row & (S_ - 1);
  int tok = tgt[row];
  float2 e = ((const float2*)emb)[tok * 256 + d2];
  float2 pp = ((const float2*)pos)[s * 256 + d2];
  ((uint*)x16)[p] = pack2(e.x + pp.x, e.y + pp.y);
}

// === 128x256-tile reg-staged dbuf GEMM, 64x128 wave tiles (v2) =============
// C = A[.,K](As) . W_bf16(Ws)[N][K]^T + bias.
// MODE 0: bf16(acc+bias)  1: relu  2: bf16 C+=acc  4: Q-prescale (cols<512)
// WHY: rounds 3-7 showed all pipes idle and pipelining neutral; per-iter LDS
// traffic (write+2x read of every operand byte) matches the measured wall ->
// LDS-BW-bound. Widening the wave tile 64x64 -> 64x128 cuts LDS bytes/FLOP
// by 1.33x (72KB vs 96KB per 2.1 MFLOP per block-iter). Structure otherwise
// IDENTICAL to the twice-verified round-6 kernel: BK=32, 2-stage reg pipeline
// (loads for t+1 at top of iter t; ds_write after MFMA so the vmcnt wait
// lands post-compute), one barrier per iter, scalar epilogue.
// 4 waves (2M x 2N), acc 4x8 (128 VGPR). LDS 48KB: [2 buf][A 8KB | B 16KB].
// T1 bijective XCD swizzle. Requires K%32==0, M%128==0, N%256==0, nwg%8==0.
template <int MODE>
__global__ __launch_bounds__(256) void gemm_rs(
    const ushort* __restrict__ A, const ushort* __restrict__ W,
    const float* __restrict__ bias, void* __restrict__ Cv, int N, int K,
    int As, int Ws, int Cs) {
  __shared__ ushort lsh[2][12288];  // [buf][A 0..4096 | B 4096..12288] ushorts
  const int tid = threadIdx.x;
  const int wv = tid >> 6, lane = tid & 63;

  // bijective XCD-aware block swizzle (T1)
  const int nwg = gridDim.x * gridDim.y;
  int lid = blockIdx.x + gridDim.x * blockIdx.y;
  lid = (lid & 7) * (nwg >> 3) + (lid >> 3);
  const int bx = lid % gridDim.x;
  const int by = lid / gridDim.x;
  const int m0 = by << 7, n0 = bx << 8;  // 128 (M) x 256 (N) tile

  const int wm = (wv >> 1) << 6;  // 0 / 64
  const int wn = (wv & 1) << 7;   // 0 / 128
  const int tr = lane & 15, tq = lane >> 4;

  // staging map (proven gemm_bt pattern): thread covers 16B at offsets lin0
  // and lin0+512 within each 4096-ushort (128-row x 32-col) panel.
  const int lin0 = wv * 1024 + lane * 8;
  const int am0 = lin0 >> 5, ac0 = lin0 & 31;
  const int lin1 = lin0 + 512;
  const int am1 = lin1 >> 5, ac1 = lin1 & 31;

  const ushort* pa0 = A + (size_t)(m0 + am0) * As + ac0;
  const ushort* pa1 = A + (size_t)(m0 + am1) * As + ac1;
  const ushort* pb0 = W + (size_t)(n0 + am0) * Ws + ac0;
  const ushort* pb1 = W + (size_t)(n0 + am1) * Ws + ac1;
  const ushort* pb2 = W + (size_t)(n0 + 128 + am0) * Ws + ac0;
  const ushort* pb3 = W + (size_t)(n0 + 128 + am1) * Ws + ac1;

  f32x4 acc[4][8];
#pragma unroll
  for (int i = 0; i < 4; ++i)
#pragma unroll
    for (int j = 0; j < 8; ++j) acc[i][j] = (f32x4)(0.f);

  const int KT = K >> 5;  // BK = 32

  uint4 ra0, ra1, rb0, rb1, rb2, rb3;  // staged K-tile (one reg set)

#define LOADR(t)                                                               \
  do {                                                                         \
    const int kb_ = (t) << 5;                                                  \
    ra0 = *(const uint4*)(pa0 + kb_);                                          \
    ra1 = *(const uint4*)(pa1 + kb_);                                          \
    rb0 = *(const uint4*)(pb0 + kb_);                                          \
    rb1 = *(const uint4*)(pb1 + kb_);                                          \
    rb2 = *(const uint4*)(pb2 + kb_);                                          \
    rb3 = *(const uint4*)(pb3 + kb_);                                          \
  } while (0)
#define WRITR(d)                                                               \
  do {                                                                         \
    *(uint4*)&lsh[d][lin0] = ra0;                                              \
    *(uint4*)&lsh[d][lin1] = ra1;                                              \
    *(uint4*)&lsh[d][4096 + lin0] = rb0;                                       \
    *(uint4*)&lsh[d][4096 + lin1] = rb1;                                       \
    *(uint4*)&lsh[d][8192 + lin0] = rb2;                                       \
    *(uint4*)&lsh[d][8192 + lin1] = rb3;                                       \
  } while (0)

  LOADR(0);
  WRITR(0);
  __syncthreads();

  for (int t = 0; t < KT; ++t) {
    const int d = t & 1;
    if (t + 1 < KT) LOADR(t + 1);  // issue next-tile loads (no wait yet)
    bf16x8 av[4], bv[8];
#pragma unroll
    for (int i = 0; i < 4; ++i)
      av[i] = *(const bf16x8*)&lsh[d][(wm + i * 16 + tr) * 32 + tq * 8];
#pragma unroll
    for (int j = 0; j < 8; ++j)
      bv[j] = *(const bf16x8*)&lsh[d][4096 + (wn + j * 16 + tr) * 32 + tq * 8];
#pragma unroll
    for (int i = 0; i < 4; ++i)
#pragma unroll
      for (int j = 0; j < 8; ++j)
        acc[i][j] = __builtin_amdgcn_mfma_f32_16x16x32_bf16(av[i], bv[j],
                                                            acc[i][j], 0, 0, 0);
    // consume staged regs AFTER compute: vmcnt wait sits here, latency hidden.
    // Writes target buf d^1 (not read this iteration); the barrier at the end
    // of the previous iteration ordered them against its reads of buf d^1.
    if (t + 1 < KT) WRITR(d ^ 1);
    __syncthreads();
  }
#undef LOADR
#undef WRITR

#pragma unroll
  for (int j = 0; j < 8; ++j) {
    const int gn = n0 + wn + j * 16 + tr;
    float bj = 0.f;
    if (MODE != 2) bj = bias[gn];
    float scl = 1.f;
    if (MODE == 4) scl = (gn < 512) ? 0.18033688011112042f : 1.f;
#pragma unroll
    for (int i = 0; i < 4; ++i) {
      const int gmb = m0 + wm + i * 16 + tq * 4;
#pragma unroll
      for (int r = 0; r < 4; ++r) {
        const size_t idx = (size_t)(gmb + r) * Cs + gn;
        float v = acc[i][j][r] + bj;
        if (MODE == 1) v = fmaxf(v, 0.f);
        if (MODE == 4) v *= scl;
        if (MODE == 2) {
          ushort* C = (ushort*)Cv;
          C[idx] = f2b(b2f(C[idx]) + acc[i][j][r]);
        } else
          ((ushort*)Cv)[idx] = f2b(v);
      }
    }
  }
}

// --- MFMA GEMM (m97 structure + T1 swizzle), kept for final fc -------------
// MODE 3: fp32 acc+bias
template <int MODE>
__global__ __launch_bounds__(256) void gemm_bt(
    const ushort* __restrict__ A, const ushort* __restrict__ W,
    const float* __restrict__ bias, void* __restrict__ Cv, int N, int K,
    int As, int Ws, int Cs) {
  __shared__ ushort la[128 * 32];
  __shared__ ushort lb[128 * 32];
  const int tid = threadIdx.x;
  const int wv = tid >> 6, lane = tid & 63;

  const int nwg = gridDim.x * gridDim.y;
  int lid = blockIdx.x + gridDim.x * blockIdx.y;
  lid = (lid & 7) * (nwg >> 3) + (lid >> 3);
  const int bx = lid % gridDim.x;
  const int by = lid / gridDim.x;
  const int m0 = by << 7, n0 = bx << 7;

  const int wm = (wv >> 1) << 6, wn = (wv & 1) << 6;
  const int tr = lane & 15, tq = lane >> 4;

  const int lin0 = wv * 1024 + lane * 8;
  const int lin1 = lin0 + 512;
  const int am0 = lin0 >> 5, ac0 = lin0 & 31;
  const int am1 = lin1 >> 5, ac1 = lin1 & 31;

  const ushort* pa0 = A + (size_t)(m0 + am0) * As + ac0;
  const ushort* pa1 = A + (size_t)(m0 + am1) * As + ac1;
  const ushort* pb0 = W + (size_t)(n0 + am0) * Ws + ac0;
  const ushort* pb1 = W + (size_t)(n0 + am1) * Ws + ac1;
  ushort* la0 = &la[wv * 1024];
  ushort* la1 = &la[wv * 1024 + 512];
  ushort* lb0 = &lb[wv * 1024];
  ushort* lb1 = &lb[wv * 1024 + 512];

  f32x4 acc[4][4];
#pragma unroll
  for (int i = 0; i < 4; ++i)
#pragma unroll
    for (int j = 0; j < 4; ++j) acc[i][j] = (f32x4)(0.f);

  const int KT = K >> 5;
  for (int kt = 0; kt < KT; ++kt) {
    const int kb = kt << 5;
    GLOAD16(pa0 + kb, la0);
    GLOAD16(pa1 + kb, la1);
    GLOAD16(pb0 + kb, lb0);
    GLOAD16(pb1 + kb, lb1);
    __syncthreads();
    bf16x8 av[4], bv[4];
#pragma unroll
    for (int i = 0; i < 4; ++i)
      av[i] = *(const bf16x8*)&la[(wm + i * 16 + tr) * 32 + tq * 8];
#pragma unroll
    for (int j = 0; j < 4; ++j)
      bv[j] = *(const bf16x8*)&lb[(wn + j * 16 + tr) * 32 + tq * 8];
#pragma unroll
    for (int i = 0; i < 4; ++i)
#pragma unroll
      for (int j = 0; j < 4; ++j)
        acc[i][j] =
            __builtin_amdgcn_mfma_f32_16x16x32_bf16(av[i], bv[j], acc[i][j], 0, 0, 0);
    __syncthreads();
  }

#pragma unroll
  for (int j = 0; j < 4; ++j) {
    const int gn = n0 + wn + j * 16 + tr;
    float bj = 0.f;
    if (MODE != 2) bj = bias[gn];
    float scl = 1.f;
    if (MODE == 4) scl = (gn < 512) ? 0.18033688011112042f : 1.f;
#pragma unroll
    for (int i = 0; i < 4; ++i) {
      const int gmb = m0 + wm + i * 16 + tq * 4;
#pragma unroll
      for (int r = 0; r < 4; ++r) {
        const size_t idx = (size_t)(gmb + r) * Cs + gn;
        float v = acc[i][j][r] + bj;
        if (MODE == 1) v = fmaxf(v, 0.f);
        if (MODE == 4) v *= scl;
        if (MODE == 3)
          ((float*)Cv)[idx] = v;
        else if (MODE == 2) {
          ushort* C = (ushort*)Cv;
          C[idx] = f2b(b2f(C[idx]) + acc[i][j][r]);
        } else
          ((ushort*)Cv)[idx] = f2b(v);
      }
    }
  }
}

// --- batched MFMA GEMM, W fp32 converted during staging (Round-4-verified) --
// C_z = A_z[.,K](As) . W_z(Ws)[N][K]^T + bias_z ; z = blockIdx.z
__global__ __launch_bounds__(256) void gemm_btf(
    const ushort* __restrict__ A0, long zA, const float* __restrict__ W0,
    long zW, const float* __restrict__ bias0, long zb, ushort* __restrict__ C0,
    long zC, int N, int K, int As, int Ws, int Cs) {
  const int zz = blockIdx.z;
  const ushort* A = A0 + zA * zz;
  const float* W = W0 + zW * zz;
  const float* bias = bias0 + zb * zz;
  ushort* C = C0 + zC * zz;

  __shared__ ushort la[128 * 32];
  __shared__ ushort lb[128 * 32];
  const int tid = threadIdx.x;
  const int wv = tid >> 6, lane = tid & 63;
  const int m0 = blockIdx.y << 7, n0 = blockIdx.x << 7;
  const int wm = (wv >> 1) << 6, wn = (wv & 1) << 6;
  const int tr = lane & 15, tq = lane >> 4;

  const int lin0 = wv * 1024 + lane * 8;
  const int lin1 = lin0 + 512;
  const int am0 = lin0 >> 5, ac0 = lin0 & 31;
  const int am1 = lin1 >> 5, ac1 = lin1 & 31;

  const ushort* pa0 = A + (size_t)(m0 + am0) * As + ac0;
  const ushort* pa1 = A + (size_t)(m0 + am1) * As + ac1;
  const float* pb0 = W + (size_t)(n0 + am0) * Ws + ac0;
  const float* pb1 = W + (size_t)(n0 + am1) * Ws + ac1;

  f32x4 acc[4][4];
#pragma unroll
  for (int i = 0; i < 4; ++i)
#pragma unroll
    for (int j = 0; j < 4; ++j) acc[i][j] = (f32x4)(0.f);

  const int KT = K >> 5;
  for (int kt = 0; kt < KT; ++kt) {
    const int kb = kt << 5;
    uint4 ra0 = *(const uint4*)(pa0 + kb);
    uint4 ra1 = *(const uint4*)(pa1 + kb);
    float4 f00 = *(const float4*)(pb0 + kb);
    float4 f01 = *(const float4*)(pb0 + kb + 4);
    float4 f10 = *(const float4*)(pb1 + kb);
    float4 f11 = *(const float4*)(pb1 + kb + 4);
    uint4 rb0 = make_uint4(pack2(f00.x, f00.y), pack2(f00.z, f00.w),
                           pack2(f01.x, f01.y), pack2(f01.z, f01.w));
    uint4 rb1 = make_uint4(pack2(f10.x, f10.y), pack2(f10.z, f10.w),
                           pack2(f11.x, f11.y), pack2(f11.z, f11.w));
    __syncthreads();
    *(uint4*)&la[lin0] = ra0;
    *(uint4*)&la[lin1] = ra1;
    *(uint4*)&lb[lin0] = rb0;
    *(uint4*)&lb[lin1] = rb1;
    __syncthreads();
    bf16x8 av[4], bv[4];
#pragma unroll
    for (int i = 0; i < 4; ++i)
      av[i] = *(const bf16x8*)&la[(wm + i * 16 + tr) * 32 + tq * 8];
#pragma unroll
    for (int j = 0; j < 4; ++j)
      bv[j] = *(const bf16x8*)&lb[(wn + j * 16 + tr) * 32 + tq * 8];
#pragma unroll
    for (int i = 0; i < 4; ++i)
#pragma unroll
      for (int j = 0; j < 4; ++j)
        acc[i][j] =
            __builtin_amdgcn_mfma_f32_16x16x32_bf16(av[i], bv[j], acc[i][j], 0, 0, 0);
  }

#pragma unroll
  for (int j = 0; j < 4; ++j) {
    const int gn = n0 + wn + j * 16 + tr;
    const float bj = bias[gn];
#pragma unroll
    for (int i = 0; i < 4; ++i) {
      const int gmb = m0 + wm + i * 16 + tq * 4;
#pragma unroll
      for (int r = 0; r < 4; ++r)
        C[(size_t)(gmb + r) * Cs + gn] = f2b(acc[i][j][r] + bj);
    }
  }
}

// ---------------- MFMA causal attention v3 ----------------
// grid (2, H, B), 128 threads (2 waves). Wave g owns q-chunk qc=2*qp+g.
// K staged [key][d]; V staged TRANSPOSED [d][key] so PV B-frags are b128.
// Q pre-scaled by log2(e)/8 in QKV GEMM. In-place output over q-slice.
// P relay is per-wave LDS (in-order LDS pipe) -> no barrier between P and PV.
__global__ __launch_bounds__(128) void attn_mfma(ushort* __restrict__ qkv) {
  __shared__ ushort lk[64 * 72];      // K chunk  [key][64+8]
  __shared__ ushort lvT[64 * 72];     // V^T      [d][64+8]
  __shared__ ushort lp[2 * 64 * 72];  // per-wave P [qrow][64+8]
  const int qp = blockIdx.x, h = blockIdx.y, b = blockIdx.z;
  const int tid = threadIdx.x;
  const int g = tid >> 6, lane = tid & 63;
  const int tr = lane & 15, tq = lane >> 4;
  const int qc = qp * 2 + g;
  const int q0 = qc << 6;
  ushort* myp = &lp[g * 64 * 72];

  bf16x8 qf[4][2];
#pragma unroll
  for (int i = 0; i < 4; ++i)
#pragma unroll
    for (int s = 0; s < 2; ++s)
      qf[i][s] = *(const bf16x8*)(qkv +
                                  (size_t)(b * 256 + q0 + i * 16 + tr) * 1536 +
                                  h * 64 + s * 32 + tq * 8);

  f32x4 o[4][4];
  float pl[4][4];
#pragma unroll
  for (int i = 0; i < 4; ++i)
#pragma unroll
    for (int j = 0; j < 4; ++j) {
      o[i][j] = (f32x4)(0.f);
      pl[i][j] = 0.f;
    }

  const int key = tid >> 1, half = tid & 1;
  const int cmax = qp * 2 + 1;
  for (int c = 0; c <= cmax; ++c) {
    __syncthreads();  // protect prior chunk's lk/lvT reads
    const ushort* gk =
        qkv + (size_t)(b * 256 + c * 64 + key) * 1536 + 512 + h * 64 + half * 32;
#pragma unroll
    for (int u = 0; u < 4; ++u)
      *(uint4*)&lk[key * 72 + half * 32 + u * 8] = *(const uint4*)(gk + u * 8);
    ushort vloc[32];
#pragma unroll
    for (int u = 0; u < 4; ++u)
      *(uint4*)&vloc[u * 8] = *(const uint4*)(gk + 512 + u * 8);
#pragma unroll
    for (int dd = 0; dd < 32; ++dd)
      lvT[(half * 32 + dd) * 72 + key] = vloc[dd];
    __syncthreads();

    if (c <= qc) {
      // S = Q . K^T
      f32x4 Sv[4][4];
#pragma unroll
      for (int i = 0; i < 4; ++i)
#pragma unroll
        for (int j = 0; j < 4; ++j) Sv[i][j] = (f32x4)(0.f);
      bf16x8 kf[4][2];
#pragma unroll
      for (int j = 0; j < 4; ++j)
#pragma unroll
        for (int s = 0; s < 2; ++s)
          kf[j][s] = *(const bf16x8*)&lk[(j * 16 + tr) * 72 + s * 32 + tq * 8];
#pragma unroll
      for (int i = 0; i < 4; ++i)
#pragma unroll
        for (int j = 0; j < 4; ++j) {
          Sv[i][j] = __builtin_amdgcn_mfma_f32_16x16x32_bf16(qf[i][0], kf[j][0],
                                                             Sv[i][j], 0, 0, 0);
          Sv[i][j] = __builtin_amdgcn_mfma_f32_16x16x32_bf16(qf[i][1], kf[j][1],
                                                             Sv[i][j], 0, 0, 0);
        }
      // exp2 (Q pre-scaled) + causal mask + partial rowsums + P -> own LDS
      const bool diag = (c == qc);
#pragma unroll
      for (int i = 0; i < 4; ++i)
#pragma unroll
        for (int j = 0; j < 4; ++j)
#pragma unroll
          for (int r = 0; r < 4; ++r) {
            float e = exp2f(Sv[i][j][r]);
            if (diag && (j * 16 + tr) > (i * 16 + tq * 4 + r)) e = 0.f;
            pl[i][r] += e;
            myp[(i * 16 + tq * 4 + r) * 72 + j * 16 + tr] =
                (ushort)(__float_as_uint(e) >> 16);  // trunc: P in [0,1]
          }
      // O += P . V  (same-wave LDS RAW: in-order DS pipe, no barrier)
#pragma unroll
      for (int s = 0; s < 2; ++s) {
        bf16x8 vf[4], af[4];
#pragma unroll
        for (int jn = 0; jn < 4; ++jn)
          vf[jn] = *(const bf16x8*)&lvT[(jn * 16 + tr) * 72 + s * 32 + tq * 8];
#pragma unroll
        for (int im = 0; im < 4; ++im)
          af[im] = *(const bf16x8*)&myp[(im * 16 + tr) * 72 + s * 32 + tq * 8];
#pragma unroll
        for (int im = 0; im < 4; ++im)
#pragma unroll
          for (int jn = 0; jn < 4; ++jn)
            o[im][jn] = __builtin_amdgcn_mfma_f32_16x16x32_bf16(af[im], vf[jn],
                                                                o[im][jn], 0, 0, 0);
      }
    }
  }

#pragma unroll
  for (int i = 0; i < 4; ++i)
#pragma unroll
    for (int r = 0; r < 4; ++r) {
      float v = pl[i][r];
      v += __shfl_xor(v, 1, 64);
      v += __shfl_xor(v, 2, 64);
      v += __shfl_xor(v, 4, 64);
      v += __shfl_xor(v, 8, 64);
      pl[i][r] = 1.f / v;
    }

#pragma unroll
  for (int i = 0; i < 4; ++i)
#pragma unroll
    for (int j = 0; j < 4; ++j)
#pragma unroll
      for (int r = 0; r < 4; ++r)
        qkv[(size_t)(b * 256 + q0 + i * 16 + tq * 4 + r) * 1536 + h * 64 +
            j * 16 + tr] = f2b(o[i][j][r] * pl[i][r]);
}

// ---- fused LN1+LN2: x = LN2(LN1(x + d1) + cavec16[b]) ---------------------
__global__ __launch_bounds__(256) void ln12_kernel(
    ushort* __restrict__ x16, const uint* __restrict__ d1,
    const uint* __restrict__ cavec, const float* __restrict__ s1,
    const float* __restrict__ b1, const float* __restrict__ s2,
    const float* __restrict__ b2p) {
  const int r = blockIdx.x, t = threadIdx.x;
  const int lane = t & 63, wv = t >> 6;
  uint* xr = (uint*)x16 + (size_t)r * 256;
  uint xu = xr[t];
  uint du = d1[(size_t)r * 768 + t];
  float v0 = blo(xu) + blo(du), v1 = bhi(xu) + bhi(du);
  __shared__ float redA[4][2], redB[4][2];
  float sm = v0 + v1, sq = v0 * v0 + v1 * v1;
#pragma unroll
  for (int o = 32; o > 0; o >>= 1) {
    sm += __shfl_xor(sm, o, 64);
    sq += __shfl_xor(sq, o, 64);
  }
  if (lane == 0) {
    redA[wv][0] = sm;
    redA[wv][1] = sq;
  }
  __syncthreads();
  sm = redA[0][0] + redA[1][0] + redA[2][0] + redA[3][0];
  sq = redA[0][1] + redA[1][1] + redA[2][1] + redA[3][1];
  float mean = sm * (1.f / 512.f);
  float var = sq * (1.f / 512.f) - mean * mean;
  float rs = rsqrtf(var + 1e-5f);
  float2 sa = ((const float2*)s1)[t];
  float2 ba = ((const float2*)b1)[t];
  uint cu = cavec[(size_t)(r >> 8) * 256 + t];
  float w0 = (v0 - mean) * rs * sa.x + ba.x + blo(cu);
  float w1 = (v1 - mean) * rs * sa.y + ba.y + bhi(cu);
  sm = w0 + w1;
  sq = w0 * w0 + w1 * w1;
#pragma unroll
  for (int o = 32; o > 0; o >>= 1) {
    sm += __shfl_xor(sm, o, 64);
    sq += __shfl_xor(sq, o, 64);
  }
  if (lane == 0) {
    redB[wv][0] = sm;
    redB[wv][1] = sq;
  }
  __syncthreads();
  sm = redB[0][0] + redB[1][0] + redB[2][0] + redB[3][0];
  sq = redB[0][1] + redB[1][1] + redB[2][1] + redB[3][1];
  mean = sm * (1.f / 512.f);
  var = sq * (1.f / 512.f) - mean * mean;
  rs = rsqrtf(var + 1e-5f);
  float2 sb = ((const float2*)s2)[t];
  float2 bb = ((const float2*)b2p)[t];
  float y0 = (w0 - mean) * rs * sb.x + bb.x;
  float y1 = (w1 - mean) * rs * sb.y + bb.y;
  xr[t] = pack2(y0, y1);
}

// -------- LayerNorm: x16 = bf16(LN(x16 + delta) * sc + bi), in place --------
__global__ __launch_bounds__(256) void ln_kernel(
    ushort* __restrict__ x16, const uint* __restrict__ delta, int DsU,
    const float* __restrict__ sc, const float* __restrict__ bi) {
  const int r = blockIdx.x, t = threadIdx.x;
  const int lane = t & 63, wv = t >> 6;
  uint* xr = (uint*)x16 + (size_t)r * 256;
  uint xu = xr[t];
  uint du = delta[(size_t)r * DsU + t];
  float v0 = blo(xu) + blo(du), v1 = bhi(xu) + bhi(du);
  float sm = v0 + v1, sq = v0 * v0 + v1 * v1;
#pragma unroll
  for (int o = 32; o > 0; o >>= 1) {
    sm += __shfl_xor(sm, o, 64);
    sq += __shfl_xor(sq, o, 64);
  }
  __shared__ float red[4][2];
  if (lane == 0) {
    red[wv][0] = sm;
    red[wv][1] = sq;
  }
  __syncthreads();
  sm = red[0][0] + red[1][0] + red[2][0] + red[3][0];
  sq = red[0][1] + red[1][1] + red[2][1] + red[3][1];
  float mean = sm * (1.f / 512.f);
  float var = sq * (1.f / 512.f) - mean * mean;
  float rs = rsqrtf(var + 1e-5f);
  float2 s2 = ((const float2*)sc)[t];
  float2 b2 = ((const float2*)bi)[t];
  float y0 = (v0 - mean) * rs * s2.x + b2.x;
  float y1 = (v1 - mean) * rs * s2.y + b2.y;
  xr[t] = pack2(y0, y1);
}

extern "C" void kernel_launch(void* const* d_in, const int* in_sizes, int n_in,
                              void* d_out, int out_size, void* d_ws,
                              size_t ws_size, hipStream_t stream) {
  (void)in_sizes; (void)n_in; (void)out_size; (void)ws_size;
  const float* z = (const float*)d_in[0];
  const int* tgt = (const int*)d_in[1];
  const float* emb = (const float*)d_in[2];
  const float* pos = (const float*)d_in[3];
  const float* projw = (const float*)d_in[4];
  const float* projb = (const float*)d_in[5];
  const float* saw = (const float*)d_in[6];
  const float* sab = (const float*)d_in[7];
  const float* saow = (const float*)d_in[8];
  const float* saob = (const float*)d_in[9];
  const float* caw = (const float*)d_in[10];
  const float* cab = (const float*)d_in[11];
  const float* caow = (const float*)d_in[12];
  const float* caob = (const float*)d_in[13];
  const float* ln1s = (const float*)d_in[14];
  const float* ln1b = (const float*)d_in[15];
  const float* ln2s = (const float*)d_in[16];
  const float* ln2b = (const float*)d_in[17];
  const float* ln3s = (const float*)d_in[18];
  const float* ln3b = (const float*)d_in[19];
  const float* ff1w = (const float*)d_in[20];
  const float* ff1b = (const float*)d_in[21];
  const float* ff2w = (const float*)d_in[22];
  const float* ff2b = (const float*)d_in[23];
  const float* fcw = (const float*)d_in[24];
  const float* fcb = (const float*)d_in[25];

  // workspace carve — TOTAL ~103 MiB:
  // [0,16M)    x16 bf16 residual
  // [16M,64M)  qkv 48M (attn in-place; out-proj delta in dead k-slice);
  //            FF phase: hbuf 32M + fdel 16M
  // [64M,66M)  bf16 smalls: z16(128x512) memv16(128x512) cav16(6x128x512)
  //            cavec16(6x128x512) — rows 64..127 are junk (M padded to 128)
  // [66M,~103M) bf16 weights (converted once per launch)
  char* w8 = (char*)d_ws;
  ushort* x16 = (ushort*)w8;
  ushort* qkv = (ushort*)(w8 + (16u << 20));
  ushort* hbuf = qkv;
  ushort* fdel = (ushort*)(w8 + (48u << 20));
  ushort* z16 = (ushort*)(w8 + (64u << 20));
  ushort* memv16 = z16 + 128 * 512;
  ushort* cav16 = memv16 + 128 * 512;
  ushort* cavec16 = cav16 + (size_t)L_ * 128 * 512;
  ushort* wsaw = (ushort*)(w8 + (66u << 20));
  ushort* wsaow = wsaw + (size_t)L_ * 1536 * 512;
  ushort* wff1 = wsaow + (size_t)L_ * 512 * 512;
  ushort* wff2 = wff1 + (size_t)L_ * 2048 * 512;
  ushort* wfcw = wff2 + (size_t)L_ * 512 * 2048;

  // one-time weight conversions (fp32 -> bf16)
  conv_kernel<<<(L_ * 1536 * 512) / 512, 256, 0, stream>>>(saw, wsaw);
  conv_kernel<<<(L_ * 512 * 512) / 512, 256, 0, stream>>>(saow, wsaow);
  conv_kernel<<<(L_ * 2048 * 512) / 512, 256, 0, stream>>>(ff1w, wff1);
  conv_kernel<<<(L_ * 512 * 2048) / 512, 256, 0, stream>>>(ff2w, wff2);
  conv_kernel<<<(V_ * 512) / 512, 256, 0, stream>>>(fcw, wfcw);
  conv_kernel<<<(B_ * 512) / 512, 256, 0, stream>>>(z, z16);

  embed_kernel<<<16384, 256, 0, stream>>>(tgt, emb, pos, x16);

  // collapsed cross-attention (kv len 1) via padded-M MFMA, all batched:
  // memv16 = z16 . projw^T + projb
  gemm_btf<<<dim3(4, 1, 1), 256, 0, stream>>>(z16, 0, projw, 0, projb, 0,
                                              memv16, 0, 512, 512, 512, 512, 512);
  // cav16[l] = memv16 . Wv_l^T + bv_l
  gemm_btf<<<dim3(4, 1, L_), 256, 0, stream>>>(
      memv16, 0, caw + 1024 * 512, (long)1536 * 512, cab + 1024, 1536, cav16,
      (long)128 * 512, 512, 512, 512, 512, 512);
  // cavec16[l] = cav16[l] . Wo_l^T + bo_l
  gemm_btf<<<dim3(4, 1, L_), 256, 0, stream>>>(
      cav16, (long)128 * 512, caow, (long)512 * 512, caob, 512, cavec16,
      (long)128 * 512, 512, 512, 512, 512, 512);

  for (int i = 0; i < L_; ++i) {
    // QKV (+ Q pre-scale): qkv = x16 . sa_w^T + sa_b  (N=1536 -> 6 col tiles)
    gemm_rs<4><<<dim3(6, 128), 256, 0, stream>>>(
        x16, wsaw + (size_t)i * 1536 * 512, sab + i * 1536, qkv, 1536, 512, 512,
        512, 1536);
    attn_mfma<<<dim3(2, H_, B_), 128, 0, stream>>>(qkv);
    // out-proj -> dead k-slice (N=512 -> 2 col tiles)
    gemm_rs<0><<<dim3(2, 128), 256, 0, stream>>>(
        qkv, wsaow + (size_t)i * 512 * 512, saob + i * 512, qkv + 512, 512, 512,
        1536, 512, 1536);
    // fused LN1 + cross-attn add + LN2
    ln12_kernel<<<16384, 256, 0, stream>>>(
        x16, (const uint*)(qkv + 512), (const uint*)(cavec16 + (size_t)i * 128 * 512),
        ln1s + i * 512, ln1b + i * 512, ln2s + i * 512, ln2b + i * 512);
    // FFN split into two DFF=1024 chunks (N=1024 -> 4 tiles; N=512 -> 2)
    gemm_rs<1><<<dim3(4, 128), 256, 0, stream>>>(
        x16, wff1 + (size_t)i * 2048 * 512, ff1b + i * 2048, hbuf, 1024, 512,
        512, 512, 1024);
    gemm_rs<0><<<dim3(2, 128), 256, 0, stream>>>(
        hbuf, wff2 + (size_t)i * 512 * 2048, ff2b + i * 512, fdel, 512, 1024,
        1024, 2048, 512);
    gemm_rs<1><<<dim3(4, 128), 256, 0, stream>>>(
        x16, wff1 + ((size_t)i * 2048 + 1024) * 512, ff1b + i * 2048 + 1024,
        hbuf, 1024, 512, 512, 512, 1024);
    gemm_rs<2><<<dim3(2, 128), 256, 0, stream>>>(
        hbuf, wff2 + (size_t)i * 512 * 2048 + 1024, (const float*)0, fdel, 512,
        1024, 1024, 2048, 512);
    ln_kernel<<<16384, 256, 0, stream>>>(x16, (const uint*)fdel, 256,
                                         ln3s + i * 512, ln3b + i * 512);
  }
  gemm_bt<3><<<dim3(1, 128), 256, 0, stream>>>(x16, wfcw, fcb, d_out, 128, 512,
                                               512, 512, 128);
}

// Round 9
// 1713.663 us; speedup vs baseline: 1.1109x; 1.1109x over previous
//
#include <hip/hip_runtime.h>

typedef unsigned int uint;
typedef unsigned short ushort;

typedef __attribute__((ext_vector_type(8))) __bf16 bf16x8;
typedef __attribute__((ext_vector_type(4))) float f32x4;

#define B_ 64
#define S_ 256
#define D_ 512
#define H_ 8
#define DFF_ 2048
#define V_ 128
#define L_ 6
#define BS_ (B_ * S_)

__device__ __forceinline__ float blo(uint u) { return __uint_as_float(u << 16); }
__device__ __forceinline__ float bhi(uint u) { return __uint_as_float(u & 0xffff0000u); }
__device__ __forceinline__ float b2f(ushort u) { return __uint_as_float(((uint)u) << 16); }
__device__ __forceinline__ ushort f2b(float f) {
  uint u = __float_as_uint(f);
  return (ushort)((u + 0x7fffu + ((u >> 16) & 1u)) >> 16);  // RTNE
}
__device__ __forceinline__ uint pack2(float a, float b) {
  return (uint)f2b(a) | ((uint)f2b(b) << 16);
}

#define GLOAD16(gp, lp)                                                        \
  __builtin_amdgcn_global_load_lds(                                            \
      (const __attribute__((address_space(1))) void*)(gp),                     \
      (__attribute__((address_space(3))) void*)(lp), 16, 0, 0)

// -------- fp32 -> bf16 bulk conversion (one-time per launch) ---------------
__global__ __launch_bounds__(256) void conv_kernel(const float* __restrict__ src,
                                                   ushort* __restrict__ dst) {
  size_t p = (size_t)blockIdx.x * 256 + threadIdx.x;
  float2 v = ((const float2*)src)[p];
  ((uint*)dst)[p] = pack2(v.x, v.y);
}

// -------- embedding: x16 = bf16(emb[tgt] + pos); emb/pos fp32 ---------------
__global__ __launch_bounds__(256) void embed_kernel(
    const int* __restrict__ tgt, const float* __restrict__ emb,
    const float* __restrict__ pos, ushort* __restrict__ x16) {
  int p = blockIdx.x * 256 + threadIdx.x;
  int row = p >> 8;
  int d2 = p & 255;
  int s = row & (S_ - 1);
  int tok = tgt[row];
  float2 e = ((const float2*)emb)[tok * 256 + d2];
  float2 pp = ((const float2*)pos)[s * 256 + d2];
  ((uint*)x16)[p] = pack2(e.x + pp.x, e.y + pp.y);
}

// === register-staged double-buffered BK=32 MFMA GEMM (round-6 struct, v3) ===
// C = A[.,K](As) . W_bf16(Ws)[N][K]^T + bias. 128x128 tile, 4 waves.
// MODE 0: bf16(acc+bias)  1: relu  2: bf16 C+=acc  4: Q-prescale (cols<512)
// v3 vs round-6 (1611us verified): BK 64 -> 32, halving LDS 64KB -> 32KB.
// Round-8 post-mortem: round-6 was LDS-CAPACITY capped at 2 blocks/CU (8
// waves) -> barrier-chain stalls had no other-block work to overlap with
// (occupancy 16.5%, all pipes idle, LDS BW only ~32 B/cy of 85). 32KB LDS
// admits up to 5 blocks/CU; VGPR also drops (smaller staged set + 8 frags).
// Pipeline unchanged: loads for tile t+1 issued at top of iter t (async),
// ds_write AFTER the MFMA block so the compiler's vmcnt wait lands
// post-compute; one barrier per iter. T1 bijective XCD swizzle.
// Requires K%32==0, M%128==0, N%128==0, nwg%8==0.
template <int MODE>
__global__ __launch_bounds__(256) void gemm_rs(
    const ushort* __restrict__ A, const ushort* __restrict__ W,
    const float* __restrict__ bias, void* __restrict__ Cv, int N, int K,
    int As, int Ws, int Cs) {
  __shared__ ushort lsh[2][8192];  // [buf][A 0..4096 | B 4096..8192] ushorts
  const int tid = threadIdx.x;
  const int wv = tid >> 6, lane = tid & 63;

  // bijective XCD-aware block swizzle (T1)
  const int nwg = gridDim.x * gridDim.y;
  int lid = blockIdx.x + gridDim.x * blockIdx.y;
  lid = (lid & 7) * (nwg >> 3) + (lid >> 3);
  const int bx = lid % gridDim.x;
  const int by = lid / gridDim.x;
  const int m0 = by << 7, n0 = bx << 7;

  const int wm = (wv >> 1) << 6, wn = (wv & 1) << 6;
  const int tr = lane & 15, tq = lane >> 4;

  // staging map (proven gemm_bt pattern): thread covers 16B at offsets lin0
  // and lin0+512 within each 4096-ushort (128-row x 32-col) panel.
  const int lin0 = wv * 1024 + lane * 8;
  const int am0 = lin0 >> 5, ac0 = lin0 & 31;
  const int lin1 = lin0 + 512;
  const int am1 = lin1 >> 5, ac1 = lin1 & 31;

  const ushort* pa0 = A + (size_t)(m0 + am0) * As + ac0;
  const ushort* pa1 = A + (size_t)(m0 + am1) * As + ac1;
  const ushort* pb0 = W + (size_t)(n0 + am0) * Ws + ac0;
  const ushort* pb1 = W + (size_t)(n0 + am1) * Ws + ac1;

  f32x4 acc[4][4];
#pragma unroll
  for (int i = 0; i < 4; ++i)
#pragma unroll
    for (int j = 0; j < 4; ++j) acc[i][j] = (f32x4)(0.f);

  const int KT = K >> 5;  // BK = 32

  uint4 ra0, ra1, rb0, rb1;  // staged K-tile (static regs)

#define LOADR(t)                                                               \
  do {                                                                         \
    const int kb_ = (t) << 5;                                                  \
    ra0 = *(const uint4*)(pa0 + kb_);                                          \
    ra1 = *(const uint4*)(pa1 + kb_);                                          \
    rb0 = *(const uint4*)(pb0 + kb_);                                          \
    rb1 = *(const uint4*)(pb1 + kb_);                                          \
  } while (0)
#define WRITR(d)                                                               \
  do {                                                                         \
    *(uint4*)&lsh[d][lin0] = ra0;                                              \
    *(uint4*)&lsh[d][lin1] = ra1;                                              \
    *(uint4*)&lsh[d][4096 + lin0] = rb0;                                       \
    *(uint4*)&lsh[d][4096 + lin1] = rb1;                                       \
  } while (0)

  LOADR(0);
  WRITR(0);
  __syncthreads();

  for (int t = 0; t < KT; ++t) {
    const int d = t & 1;
    if (t + 1 < KT) LOADR(t + 1);  // issue next-tile loads (no wait yet)
    bf16x8 av[4], bv[4];
#pragma unroll
    for (int i = 0; i < 4; ++i)
      av[i] = *(const bf16x8*)&lsh[d][(wm + i * 16 + tr) * 32 + tq * 8];
#pragma unroll
    for (int j = 0; j < 4; ++j)
      bv[j] = *(const bf16x8*)&lsh[d][4096 + (wn + j * 16 + tr) * 32 + tq * 8];
#pragma unroll
    for (int i = 0; i < 4; ++i)
#pragma unroll
      for (int j = 0; j < 4; ++j)
        acc[i][j] = __builtin_amdgcn_mfma_f32_16x16x32_bf16(av[i], bv[j],
                                                            acc[i][j], 0, 0, 0);
    // consume staged regs AFTER compute: vmcnt wait sits here, latency hidden.
    // Writes target buf d^1 (not read this iteration); the barrier at the end
    // of the previous iteration ordered them against its reads of buf d^1.
    if (t + 1 < KT) WRITR(d ^ 1);
    __syncthreads();
  }
#undef LOADR
#undef WRITR

#pragma unroll
  for (int j = 0; j < 4; ++j) {
    const int gn = n0 + wn + j * 16 + tr;
    float bj = 0.f;
    if (MODE != 2) bj = bias[gn];
    float scl = 1.f;
    if (MODE == 4) scl = (gn < 512) ? 0.18033688011112042f : 1.f;
#pragma unroll
    for (int i = 0; i < 4; ++i) {
      const int gmb = m0 + wm + i * 16 + tq * 4;
#pragma unroll
      for (int r = 0; r < 4; ++r) {
        const size_t idx = (size_t)(gmb + r) * Cs + gn;
        float v = acc[i][j][r] + bj;
        if (MODE == 1) v = fmaxf(v, 0.f);
        if (MODE == 4) v *= scl;
        if (MODE == 2) {
          ushort* C = (ushort*)Cv;
          C[idx] = f2b(b2f(C[idx]) + acc[i][j][r]);
        } else
          ((ushort*)Cv)[idx] = f2b(v);
      }
    }
  }
}

// --- MFMA GEMM (m97 structure + T1 swizzle), kept for final fc -------------
// MODE 3: fp32 acc+bias
template <int MODE>
__global__ __launch_bounds__(256) void gemm_bt(
    const ushort* __restrict__ A, const ushort* __restrict__ W,
    const float* __restrict__ bias, void* __restrict__ Cv, int N, int K,
    int As, int Ws, int Cs) {
  __shared__ ushort la[128 * 32];
  __shared__ ushort lb[128 * 32];
  const int tid = threadIdx.x;
  const int wv = tid >> 6, lane = tid & 63;

  const int nwg = gridDim.x * gridDim.y;
  int lid = blockIdx.x + gridDim.x * blockIdx.y;
  lid = (lid & 7) * (nwg >> 3) + (lid >> 3);
  const int bx = lid % gridDim.x;
  const int by = lid / gridDim.x;
  const int m0 = by << 7, n0 = bx << 7;

  const int wm = (wv >> 1) << 6, wn = (wv & 1) << 6;
  const int tr = lane & 15, tq = lane >> 4;

  const int lin0 = wv * 1024 + lane * 8;
  const int lin1 = lin0 + 512;
  const int am0 = lin0 >> 5, ac0 = lin0 & 31;
  const int am1 = lin1 >> 5, ac1 = lin1 & 31;

  const ushort* pa0 = A + (size_t)(m0 + am0) * As + ac0;
  const ushort* pa1 = A + (size_t)(m0 + am1) * As + ac1;
  const ushort* pb0 = W + (size_t)(n0 + am0) * Ws + ac0;
  const ushort* pb1 = W + (size_t)(n0 + am1) * Ws + ac1;
  ushort* la0 = &la[wv * 1024];
  ushort* la1 = &la[wv * 1024 + 512];
  ushort* lb0 = &lb[wv * 1024];
  ushort* lb1 = &lb[wv * 1024 + 512];

  f32x4 acc[4][4];
#pragma unroll
  for (int i = 0; i < 4; ++i)
#pragma unroll
    for (int j = 0; j < 4; ++j) acc[i][j] = (f32x4)(0.f);

  const int KT = K >> 5;
  for (int kt = 0; kt < KT; ++kt) {
    const int kb = kt << 5;
    GLOAD16(pa0 + kb, la0);
    GLOAD16(pa1 + kb, la1);
    GLOAD16(pb0 + kb, lb0);
    GLOAD16(pb1 + kb, lb1);
    __syncthreads();
    bf16x8 av[4], bv[4];
#pragma unroll
    for (int i = 0; i < 4; ++i)
      av[i] = *(const bf16x8*)&la[(wm + i * 16 + tr) * 32 + tq * 8];
#pragma unroll
    for (int j = 0; j < 4; ++j)
      bv[j] = *(const bf16x8*)&lb[(wn + j * 16 + tr) * 32 + tq * 8];
#pragma unroll
    for (int i = 0; i < 4; ++i)
#pragma unroll
      for (int j = 0; j < 4; ++j)
        acc[i][j] =
            __builtin_amdgcn_mfma_f32_16x16x32_bf16(av[i], bv[j], acc[i][j], 0, 0, 0);
    __syncthreads();
  }

#pragma unroll
  for (int j = 0; j < 4; ++j) {
    const int gn = n0 + wn + j * 16 + tr;
    float bj = 0.f;
    if (MODE != 2) bj = bias[gn];
    float scl = 1.f;
    if (MODE == 4) scl = (gn < 512) ? 0.18033688011112042f : 1.f;
#pragma unroll
    for (int i = 0; i < 4; ++i) {
      const int gmb = m0 + wm + i * 16 + tq * 4;
#pragma unroll
      for (int r = 0; r < 4; ++r) {
        const size_t idx = (size_t)(gmb + r) * Cs + gn;
        float v = acc[i][j][r] + bj;
        if (MODE == 1) v = fmaxf(v, 0.f);
        if (MODE == 4) v *= scl;
        if (MODE == 3)
          ((float*)Cv)[idx] = v;
        else if (MODE == 2) {
          ushort* C = (ushort*)Cv;
          C[idx] = f2b(b2f(C[idx]) + acc[i][j][r]);
        } else
          ((ushort*)Cv)[idx] = f2b(v);
      }
    }
  }
}

// --- batched MFMA GEMM, W fp32 converted during staging (Round-4-verified) --
// C_z = A_z[.,K](As) . W_z(Ws)[N][K]^T + bias_z ; z = blockIdx.z
__global__ __launch_bounds__(256) void gemm_btf(
    const ushort* __restrict__ A0, long zA, const float* __restrict__ W0,
    long zW, const float* __restrict__ bias0, long zb, ushort* __restrict__ C0,
    long zC, int N, int K, int As, int Ws, int Cs) {
  const int zz = blockIdx.z;
  const ushort* A = A0 + zA * zz;
  const float* W = W0 + zW * zz;
  const float* bias = bias0 + zb * zz;
  ushort* C = C0 + zC * zz;

  __shared__ ushort la[128 * 32];
  __shared__ ushort lb[128 * 32];
  const int tid = threadIdx.x;
  const int wv = tid >> 6, lane = tid & 63;
  const int m0 = blockIdx.y << 7, n0 = blockIdx.x << 7;
  const int wm = (wv >> 1) << 6, wn = (wv & 1) << 6;
  const int tr = lane & 15, tq = lane >> 4;

  const int lin0 = wv * 1024 + lane * 8;
  const int lin1 = lin0 + 512;
  const int am0 = lin0 >> 5, ac0 = lin0 & 31;
  const int am1 = lin1 >> 5, ac1 = lin1 & 31;

  const ushort* pa0 = A + (size_t)(m0 + am0) * As + ac0;
  const ushort* pa1 = A + (size_t)(m0 + am1) * As + ac1;
  const float* pb0 = W + (size_t)(n0 + am0) * Ws + ac0;
  const float* pb1 = W + (size_t)(n0 + am1) * Ws + ac1;

  f32x4 acc[4][4];
#pragma unroll
  for (int i = 0; i < 4; ++i)
#pragma unroll
    for (int j = 0; j < 4; ++j) acc[i][j] = (f32x4)(0.f);

  const int KT = K >> 5;
  for (int kt = 0; kt < KT; ++kt) {
    const int kb = kt << 5;
    uint4 ra0 = *(const uint4*)(pa0 + kb);
    uint4 ra1 = *(const uint4*)(pa1 + kb);
    float4 f00 = *(const float4*)(pb0 + kb);
    float4 f01 = *(const float4*)(pb0 + kb + 4);
    float4 f10 = *(const float4*)(pb1 + kb);
    float4 f11 = *(const float4*)(pb1 + kb + 4);
    uint4 rb0 = make_uint4(pack2(f00.x, f00.y), pack2(f00.z, f00.w),
                           pack2(f01.x, f01.y), pack2(f01.z, f01.w));
    uint4 rb1 = make_uint4(pack2(f10.x, f10.y), pack2(f10.z, f10.w),
                           pack2(f11.x, f11.y), pack2(f11.z, f11.w));
    __syncthreads();
    *(uint4*)&la[lin0] = ra0;
    *(uint4*)&la[lin1] = ra1;
    *(uint4*)&lb[lin0] = rb0;
    *(uint4*)&lb[lin1] = rb1;
    __syncthreads();
    bf16x8 av[4], bv[4];
#pragma unroll
    for (int i = 0; i < 4; ++i)
      av[i] = *(const bf16x8*)&la[(wm + i * 16 + tr) * 32 + tq * 8];
#pragma unroll
    for (int j = 0; j < 4; ++j)
      bv[j] = *(const bf16x8*)&lb[(wn + j * 16 + tr) * 32 + tq * 8];
#pragma unroll
    for (int i = 0; i < 4; ++i)
#pragma unroll
      for (int j = 0; j < 4; ++j)
        acc[i][j] =
            __builtin_amdgcn_mfma_f32_16x16x32_bf16(av[i], bv[j], acc[i][j], 0, 0, 0);
  }

#pragma unroll
  for (int j = 0; j < 4; ++j) {
    const int gn = n0 + wn + j * 16 + tr;
    const float bj = bias[gn];
#pragma unroll
    for (int i = 0; i < 4; ++i) {
      const int gmb = m0 + wm + i * 16 + tq * 4;
#pragma unroll
      for (int r = 0; r < 4; ++r)
        C[(size_t)(gmb + r) * Cs + gn] = f2b(acc[i][j][r] + bj);
    }
  }
}

// ---------------- MFMA causal attention v3 ----------------
// grid (2, H, B), 128 threads (2 waves). Wave g owns q-chunk qc=2*qp+g.
// K staged [key][d]; V staged TRANSPOSED [d][key] so PV B-frags are b128.
// Q pre-scaled by log2(e)/8 in QKV GEMM. In-place output over q-slice.
// P relay is per-wave LDS (in-order LDS pipe) -> no barrier between P and PV.
__global__ __launch_bounds__(128) void attn_mfma(ushort* __restrict__ qkv) {
  __shared__ ushort lk[64 * 72];      // K chunk  [key][64+8]
  __shared__ ushort lvT[64 * 72];     // V^T      [d][64+8]
  __shared__ ushort lp[2 * 64 * 72];  // per-wave P [qrow][64+8]
  const int qp = blockIdx.x, h = blockIdx.y, b = blockIdx.z;
  const int tid = threadIdx.x;
  const int g = tid >> 6, lane = tid & 63;
  const int tr = lane & 15, tq = lane >> 4;
  const int qc = qp * 2 + g;
  const int q0 = qc << 6;
  ushort* myp = &lp[g * 64 * 72];

  bf16x8 qf[4][2];
#pragma unroll
  for (int i = 0; i < 4; ++i)
#pragma unroll
    for (int s = 0; s < 2; ++s)
      qf[i][s] = *(const bf16x8*)(qkv +
                                  (size_t)(b * 256 + q0 + i * 16 + tr) * 1536 +
                                  h * 64 + s * 32 + tq * 8);

  f32x4 o[4][4];
  float pl[4][4];
#pragma unroll
  for (int i = 0; i < 4; ++i)
#pragma unroll
    for (int j = 0; j < 4; ++j) {
      o[i][j] = (f32x4)(0.f);
      pl[i][j] = 0.f;
    }

  const int key = tid >> 1, half = tid & 1;
  const int cmax = qp * 2 + 1;
  for (int c = 0; c <= cmax; ++c) {
    __syncthreads();  // protect prior chunk's lk/lvT reads
    const ushort* gk =
        qkv + (size_t)(b * 256 + c * 64 + key) * 1536 + 512 + h * 64 + half * 32;
#pragma unroll
    for (int u = 0; u < 4; ++u)
      *(uint4*)&lk[key * 72 + half * 32 + u * 8] = *(const uint4*)(gk + u * 8);
    ushort vloc[32];
#pragma unroll
    for (int u = 0; u < 4; ++u)
      *(uint4*)&vloc[u * 8] = *(const uint4*)(gk + 512 + u * 8);
#pragma unroll
    for (int dd = 0; dd < 32; ++dd)
      lvT[(half * 32 + dd) * 72 + key] = vloc[dd];
    __syncthreads();

    if (c <= qc) {
      // S = Q . K^T
      f32x4 Sv[4][4];
#pragma unroll
      for (int i = 0; i < 4; ++i)
#pragma unroll
        for (int j = 0; j < 4; ++j) Sv[i][j] = (f32x4)(0.f);
      bf16x8 kf[4][2];
#pragma unroll
      for (int j = 0; j < 4; ++j)
#pragma unroll
        for (int s = 0; s < 2; ++s)
          kf[j][s] = *(const bf16x8*)&lk[(j * 16 + tr) * 72 + s * 32 + tq * 8];
#pragma unroll
      for (int i = 0; i < 4; ++i)
#pragma unroll
        for (int j = 0; j < 4; ++j) {
          Sv[i][j] = __builtin_amdgcn_mfma_f32_16x16x32_bf16(qf[i][0], kf[j][0],
                                                             Sv[i][j], 0, 0, 0);
          Sv[i][j] = __builtin_amdgcn_mfma_f32_16x16x32_bf16(qf[i][1], kf[j][1],
                                                             Sv[i][j], 0, 0, 0);
        }
      // exp2 (Q pre-scaled) + causal mask + partial rowsums + P -> own LDS
      const bool diag = (c == qc);
#pragma unroll
      for (int i = 0; i < 4; ++i)
#pragma unroll
        for (int j = 0; j < 4; ++j)
#pragma unroll
          for (int r = 0; r < 4; ++r) {
            float e = exp2f(Sv[i][j][r]);
            if (diag && (j * 16 + tr) > (i * 16 + tq * 4 + r)) e = 0.f;
            pl[i][r] += e;
            myp[(i * 16 + tq * 4 + r) * 72 + j * 16 + tr] =
                (ushort)(__float_as_uint(e) >> 16);  // trunc: P in [0,1]
          }
      // O += P . V  (same-wave LDS RAW: in-order DS pipe, no barrier)
#pragma unroll
      for (int s = 0; s < 2; ++s) {
        bf16x8 vf[4], af[4];
#pragma unroll
        for (int jn = 0; jn < 4; ++jn)
          vf[jn] = *(const bf16x8*)&lvT[(jn * 16 + tr) * 72 + s * 32 + tq * 8];
#pragma unroll
        for (int im = 0; im < 4; ++im)
          af[im] = *(const bf16x8*)&myp[(im * 16 + tr) * 72 + s * 32 + tq * 8];
#pragma unroll
        for (int im = 0; im < 4; ++im)
#pragma unroll
          for (int jn = 0; jn < 4; ++jn)
            o[im][jn] = __builtin_amdgcn_mfma_f32_16x16x32_bf16(af[im], vf[jn],
                                                                o[im][jn], 0, 0, 0);
      }
    }
  }

#pragma unroll
  for (int i = 0; i < 4; ++i)
#pragma unroll
    for (int r = 0; r < 4; ++r) {
      float v = pl[i][r];
      v += __shfl_xor(v, 1, 64);
      v += __shfl_xor(v, 2, 64);
      v += __shfl_xor(v, 4, 64);
      v += __shfl_xor(v, 8, 64);
      pl[i][r] = 1.f / v;
    }

#pragma unroll
  for (int i = 0; i < 4; ++i)
#pragma unroll
    for (int j = 0; j < 4; ++j)
#pragma unroll
      for (int r = 0; r < 4; ++r)
        qkv[(size_t)(b * 256 + q0 + i * 16 + tq * 4 + r) * 1536 + h * 64 +
            j * 16 + tr] = f2b(o[i][j][r] * pl[i][r]);
}

// ---- fused LN1+LN2: x = LN2(LN1(x + d1) + cavec16[b]) ---------------------
__global__ __launch_bounds__(256) void ln12_kernel(
    ushort* __restrict__ x16, const uint* __restrict__ d1,
    const uint* __restrict__ cavec, const float* __restrict__ s1,
    const float* __restrict__ b1, const float* __restrict__ s2,
    const float* __restrict__ b2p) {
  const int r = blockIdx.x, t = threadIdx.x;
  const int lane = t & 63, wv = t >> 6;
  uint* xr = (uint*)x16 + (size_t)r * 256;
  uint xu = xr[t];
  uint du = d1[(size_t)r * 768 + t];
  float v0 = blo(xu) + blo(du), v1 = bhi(xu) + bhi(du);
  __shared__ float redA[4][2], redB[4][2];
  float sm = v0 + v1, sq = v0 * v0 + v1 * v1;
#pragma unroll
  for (int o = 32; o > 0; o >>= 1) {
    sm += __shfl_xor(sm, o, 64);
    sq += __shfl_xor(sq, o, 64);
  }
  if (lane == 0) {
    redA[wv][0] = sm;
    redA[wv][1] = sq;
  }
  __syncthreads();
  sm = redA[0][0] + redA[1][0] + redA[2][0] + redA[3][0];
  sq = redA[0][1] + redA[1][1] + redA[2][1] + redA[3][1];
  float mean = sm * (1.f / 512.f);
  float var = sq * (1.f / 512.f) - mean * mean;
  float rs = rsqrtf(var + 1e-5f);
  float2 sa = ((const float2*)s1)[t];
  float2 ba = ((const float2*)b1)[t];
  uint cu = cavec[(size_t)(r >> 8) * 256 + t];
  float w0 = (v0 - mean) * rs * sa.x + ba.x + blo(cu);
  float w1 = (v1 - mean) * rs * sa.y + ba.y + bhi(cu);
  sm = w0 + w1;
  sq = w0 * w0 + w1 * w1;
#pragma unroll
  for (int o = 32; o > 0; o >>= 1) {
    sm += __shfl_xor(sm, o, 64);
    sq += __shfl_xor(sq, o, 64);
  }
  if (lane == 0) {
    redB[wv][0] = sm;
    redB[wv][1] = sq;
  }
  __syncthreads();
  sm = redB[0][0] + redB[1][0] + redB[2][0] + redB[3][0];
  sq = redB[0][1] + redB[1][1] + redB[2][1] + redB[3][1];
  mean = sm * (1.f / 512.f);
  var = sq * (1.f / 512.f) - mean * mean;
  rs = rsqrtf(var + 1e-5f);
  float2 sb = ((const float2*)s2)[t];
  float2 bb = ((const float2*)b2p)[t];
  float y0 = (w0 - mean) * rs * sb.x + bb.x;
  float y1 = (w1 - mean) * rs * sb.y + bb.y;
  xr[t] = pack2(y0, y1);
}

// -------- LayerNorm: x16 = bf16(LN(x16 + delta) * sc + bi), in place --------
__global__ __launch_bounds__(256) void ln_kernel(
    ushort* __restrict__ x16, const uint* __restrict__ delta, int DsU,
    const float* __restrict__ sc, const float* __restrict__ bi) {
  const int r = blockIdx.x, t = threadIdx.x;
  const int lane = t & 63, wv = t >> 6;
  uint* xr = (uint*)x16 + (size_t)r * 256;
  uint xu = xr[t];
  uint du = delta[(size_t)r * DsU + t];
  float v0 = blo(xu) + blo(du), v1 = bhi(xu) + bhi(du);
  float sm = v0 + v1, sq = v0 * v0 + v1 * v1;
#pragma unroll
  for (int o = 32; o > 0; o >>= 1) {
    sm += __shfl_xor(sm, o, 64);
    sq += __shfl_xor(sq, o, 64);
  }
  __shared__ float red[4][2];
  if (lane == 0) {
    red[wv][0] = sm;
    red[wv][1] = sq;
  }
  __syncthreads();
  sm = red[0][0] + red[1][0] + red[2][0] + red[3][0];
  sq = red[0][1] + red[1][1] + red[2][1] + red[3][1];
  float mean = sm * (1.f / 512.f);
  float var = sq * (1.f / 512.f) - mean * mean;
  float rs = rsqrtf(var + 1e-5f);
  float2 s2 = ((const float2*)sc)[t];
  float2 b2 = ((const float2*)bi)[t];
  float y0 = (v0 - mean) * rs * s2.x + b2.x;
  float y1 = (v1 - mean) * rs * s2.y + b2.y;
  xr[t] = pack2(y0, y1);
}

extern "C" void kernel_launch(void* const* d_in, const int* in_sizes, int n_in,
                              void* d_out, int out_size, void* d_ws,
                              size_t ws_size, hipStream_t stream) {
  (void)in_sizes; (void)n_in; (void)out_size; (void)ws_size;
  const float* z = (const float*)d_in[0];
  const int* tgt = (const int*)d_in[1];
  const float* emb = (const float*)d_in[2];
  const float* pos = (const float*)d_in[3];
  const float* projw = (const float*)d_in[4];
  const float* projb = (const float*)d_in[5];
  const float* saw = (const float*)d_in[6];
  const float* sab = (const float*)d_in[7];
  const float* saow = (const float*)d_in[8];
  const float* saob = (const float*)d_in[9];
  const float* caw = (const float*)d_in[10];
  const float* cab = (const float*)d_in[11];
  const float* caow = (const float*)d_in[12];
  const float* caob = (const float*)d_in[13];
  const float* ln1s = (const float*)d_in[14];
  const float* ln1b = (const float*)d_in[15];
  const float* ln2s = (const float*)d_in[16];
  const float* ln2b = (const float*)d_in[17];
  const float* ln3s = (const float*)d_in[18];
  const float* ln3b = (const float*)d_in[19];
  const float* ff1w = (const float*)d_in[20];
  const float* ff1b = (const float*)d_in[21];
  const float* ff2w = (const float*)d_in[22];
  const float* ff2b = (const float*)d_in[23];
  const float* fcw = (const float*)d_in[24];
  const float* fcb = (const float*)d_in[25];

  // workspace carve — TOTAL ~103 MiB:
  // [0,16M)    x16 bf16 residual
  // [16M,64M)  qkv 48M (attn in-place; out-proj delta in dead k-slice);
  //            FF phase: hbuf 32M + fdel 16M
  // [64M,66M)  bf16 smalls: z16(128x512) memv16(128x512) cav16(6x128x512)
  //            cavec16(6x128x512) — rows 64..127 are junk (M padded to 128)
  // [66M,~103M) bf16 weights (converted once per launch)
  char* w8 = (char*)d_ws;
  ushort* x16 = (ushort*)w8;
  ushort* qkv = (ushort*)(w8 + (16u << 20));
  ushort* hbuf = qkv;
  ushort* fdel = (ushort*)(w8 + (48u << 20));
  ushort* z16 = (ushort*)(w8 + (64u << 20));
  ushort* memv16 = z16 + 128 * 512;
  ushort* cav16 = memv16 + 128 * 512;
  ushort* cavec16 = cav16 + (size_t)L_ * 128 * 512;
  ushort* wsaw = (ushort*)(w8 + (66u << 20));
  ushort* wsaow = wsaw + (size_t)L_ * 1536 * 512;
  ushort* wff1 = wsaow + (size_t)L_ * 512 * 512;
  ushort* wff2 = wff1 + (size_t)L_ * 2048 * 512;
  ushort* wfcw = wff2 + (size_t)L_ * 512 * 2048;

  // one-time weight conversions (fp32 -> bf16)
  conv_kernel<<<(L_ * 1536 * 512) / 512, 256, 0, stream>>>(saw, wsaw);
  conv_kernel<<<(L_ * 512 * 512) / 512, 256, 0, stream>>>(saow, wsaow);
  conv_kernel<<<(L_ * 2048 * 512) / 512, 256, 0, stream>>>(ff1w, wff1);
  conv_kernel<<<(L_ * 512 * 2048) / 512, 256, 0, stream>>>(ff2w, wff2);
  conv_kernel<<<(V_ * 512) / 512, 256, 0, stream>>>(fcw, wfcw);
  conv_kernel<<<(B_ * 512) / 512, 256, 0, stream>>>(z, z16);

  embed_kernel<<<16384, 256, 0, stream>>>(tgt, emb, pos, x16);

  // collapsed cross-attention (kv len 1) via padded-M MFMA, all batched:
  // memv16 = z16 . projw^T + projb
  gemm_btf<<<dim3(4, 1, 1), 256, 0, stream>>>(z16, 0, projw, 0, projb, 0,
                                              memv16, 0, 512, 512, 512, 512, 512);
  // cav16[l] = memv16 . Wv_l^T + bv_l
  gemm_btf<<<dim3(4, 1, L_), 256, 0, stream>>>(
      memv16, 0, caw + 1024 * 512, (long)1536 * 512, cab + 1024, 1536, cav16,
      (long)128 * 512, 512, 512, 512, 512, 512);
  // cavec16[l] = cav16[l] . Wo_l^T + bo_l
  gemm_btf<<<dim3(4, 1, L_), 256, 0, stream>>>(
      cav16, (long)128 * 512, caow, (long)512 * 512, caob, 512, cavec16,
      (long)128 * 512, 512, 512, 512, 512, 512);

  for (int i = 0; i < L_; ++i) {
    // QKV (+ Q pre-scale): qkv = x16 . sa_w^T + sa_b
    gemm_rs<4><<<dim3(12, 128), 256, 0, stream>>>(
        x16, wsaw + (size_t)i * 1536 * 512, sab + i * 1536, qkv, 1536, 512, 512,
        512, 1536);
    attn_mfma<<<dim3(2, H_, B_), 128, 0, stream>>>(qkv);
    // out-proj -> dead k-slice
    gemm_rs<0><<<dim3(4, 128), 256, 0, stream>>>(
        qkv, wsaow + (size_t)i * 512 * 512, saob + i * 512, qkv + 512, 512, 512,
        1536, 512, 1536);
    // fused LN1 + cross-attn add + LN2
    ln12_kernel<<<16384, 256, 0, stream>>>(
        x16, (const uint*)(qkv + 512), (const uint*)(cavec16 + (size_t)i * 128 * 512),
        ln1s + i * 512, ln1b + i * 512, ln2s + i * 512, ln2b + i * 512);
    // FFN split into two DFF=1024 chunks
    gemm_rs<1><<<dim3(8, 128), 256, 0, stream>>>(
        x16, wff1 + (size_t)i * 2048 * 512, ff1b + i * 2048, hbuf, 1024, 512,
        512, 512, 1024);
    gemm_rs<0><<<dim3(4, 128), 256, 0, stream>>>(
        hbuf, wff2 + (size_t)i * 512 * 2048, ff2b + i * 512, fdel, 512, 1024,
        1024, 2048, 512);
    gemm_rs<1><<<dim3(8, 128), 256, 0, stream>>>(
        x16, wff1 + ((size_t)i * 2048 + 1024) * 512, ff1b + i * 2048 + 1024,
        hbuf, 1024, 512, 512, 512, 1024);
    gemm_rs<2><<<dim3(4, 128), 256, 0, stream>>>(
        hbuf, wff2 + (size_t)i * 512 * 2048 + 1024, (const float*)0, fdel, 512,
        1024, 1024, 2048, 512);
    ln_kernel<<<16384, 256, 0, stream>>>(x16, (const uint*)fdel, 256,
                                         ln3s + i * 512, ln3b + i * 512);
  }
  gemm_bt<3><<<dim3(1, 128), 256, 0, stream>>>(x16, wfcw, fcb, d_out, 128, 512,
                                               512, 512, 128);
}